// Round 13
// baseline (710.645 us; speedup 1.0000x reference)
//
#include <hip/hip_runtime.h>
#include <hip/hip_fp16.h>
#include <math.h>

// GraphConv x5 (DGL norm='both') on MI355X.
// R13: layers 3/4 gathers are COLUMN-SLICED and XCD-affine: slice =
// blockIdx&7 -> each XCD touches only its 16-col slice of xp (N x 32B =
// 3.2MB < 4MB per-XCD L2) -> gather reads become L2 hits; HBM fetch
// drops 177MB -> ~33MB/layer. Gather and GEMM split into k_gcol +
// k_lin128g. Divergence in gcol killed by degree-rank (bitonic) grouping.
// gl12 keeps the R10 lane-parallel recompute form (VALU-bound, ~125us).

#define LRELU_SLOPE 0.01f
#define XPAD 129     // 128+1: LDS bank (lane+k)%32 -> 2-way on wave64 = free
#define MAXBUCK 512  // supports N <= 131072

// ---------------- bucket-partition preprocessing ----------------

__device__ inline void chunk_range(int E, int nchunks, int cid, int& lo, int& hi) {
    int chunk = (E + nchunks - 1) / nchunks;
    lo = cid * chunk;
    hi = min(E, lo + chunk);
}

__global__ __launch_bounds__(256) void k_part_hist2(const int* __restrict__ src, const int* __restrict__ dst,
                                                    int E, int nbuck,
                                                    unsigned* __restrict__ gHistS, unsigned* __restrict__ gHistD,
                                                    unsigned* __restrict__ blockBaseS, unsigned* __restrict__ blockBaseD) {
    __shared__ unsigned hs[MAXBUCK];
    __shared__ unsigned hd[MAXBUCK];
    for (int i = threadIdx.x; i < nbuck; i += 256) { hs[i] = 0u; hd[i] = 0u; }
    __syncthreads();
    int lo, hi;
    chunk_range(E, gridDim.x, blockIdx.x, lo, hi);
    for (int e = lo + threadIdx.x; e < hi; e += 256) {
        atomicAdd(&hs[src[e] >> 8], 1u);
        atomicAdd(&hd[dst[e] >> 8], 1u);
    }
    __syncthreads();
    for (int i = threadIdx.x; i < nbuck; i += 256) {
        blockBaseS[(size_t)blockIdx.x * nbuck + i] = atomicAdd(&gHistS[i], hs[i]);
        blockBaseD[(size_t)blockIdx.x * nbuck + i] = atomicAdd(&gHistD[i], hd[i]);
    }
}

__global__ __launch_bounds__(512) void k_part_scan(const unsigned* __restrict__ gHist, int nbuck,
                                                   unsigned* __restrict__ bucketStart,
                                                   unsigned* __restrict__ row_ptr_last, unsigned Eval) {
    __shared__ unsigned s[MAXBUCK];
    int t = threadIdx.x;
    s[t] = (t < nbuck) ? gHist[t] : 0u;
    __syncthreads();
    for (int off = 1; off < MAXBUCK; off <<= 1) {
        unsigned v = (t >= off) ? s[t - off] : 0u;
        __syncthreads();
        s[t] += v;
        __syncthreads();
    }
    if (t <= nbuck) bucketStart[t] = (t == 0) ? 0u : s[t - 1];
    if (t == 0 && row_ptr_last) *row_ptr_last = Eval;
}

__global__ __launch_bounds__(256) void k_part_scatter_both(const int* __restrict__ src, const int* __restrict__ dst,
                                                           int E, int nbuck,
                                                           const unsigned* __restrict__ bstartS,
                                                           const unsigned* __restrict__ bstartD,
                                                           const unsigned* __restrict__ blockBaseS,
                                                           const unsigned* __restrict__ blockBaseD,
                                                           int2* __restrict__ pairs, int* __restrict__ srcbuf) {
    __shared__ unsigned curS[MAXBUCK];
    __shared__ unsigned curD[MAXBUCK];
    for (int i = threadIdx.x; i < nbuck; i += 256) {
        curS[i] = bstartS[i] + blockBaseS[(size_t)blockIdx.x * nbuck + i];
        curD[i] = bstartD[i] + blockBaseD[(size_t)blockIdx.x * nbuck + i];
    }
    __syncthreads();
    int lo, hi;
    chunk_range(E, gridDim.x, blockIdx.x, lo, hi);
    for (int e = lo + threadIdx.x; e < hi; e += 256) {
        int s = src[e], d = dst[e];
        unsigned posD = atomicAdd(&curD[d >> 8], 1u);
        pairs[posD] = make_int2(s, d);
        unsigned posS = atomicAdd(&curS[s >> 8], 1u);
        srcbuf[posS] = s;
    }
}

__global__ __launch_bounds__(256) void k_bucket_csr(const int2* __restrict__ pairs,
                                                    const unsigned* __restrict__ bucketStart,
                                                    unsigned* __restrict__ row_ptr,
                                                    unsigned* __restrict__ din_cnt,
                                                    int* __restrict__ csr, int n) {
    __shared__ unsigned hist[256];
    __shared__ unsigned scanw[256];
    __shared__ unsigned cur[256];
    int b = blockIdx.x, t = threadIdx.x;
    unsigned beg = bucketStart[b], end = bucketStart[b + 1];
    hist[t] = 0u;
    __syncthreads();
    for (unsigned e = beg + t; e < end; e += 256)
        atomicAdd(&hist[pairs[e].y & 255], 1u);
    __syncthreads();
    scanw[t] = hist[t];
    __syncthreads();
    for (int off = 1; off < 256; off <<= 1) {
        unsigned u = (t >= off) ? scanw[t - off] : 0u;
        __syncthreads();
        scanw[t] += u;
        __syncthreads();
    }
    unsigned excl = scanw[t] - hist[t];
    int node = (b << 8) + t;
    if (node < n) {
        row_ptr[node] = beg + excl;
        din_cnt[node] = hist[t];
    }
    cur[t] = excl;
    __syncthreads();
    for (unsigned e = beg + t; e < end; e += 256) {
        int2 p = pairs[e];
        unsigned pos = beg + atomicAdd(&cur[p.y & 255], 1u);
        csr[pos] = p.x;
    }
}

__global__ __launch_bounds__(256) void k_bucket_cnt(const int* __restrict__ vals,
                                                    const unsigned* __restrict__ bucketStart,
                                                    unsigned* __restrict__ dout_cnt, int n) {
    __shared__ unsigned hist[256];
    int b = blockIdx.x, t = threadIdx.x;
    unsigned beg = bucketStart[b], end = bucketStart[b + 1];
    hist[t] = 0u;
    __syncthreads();
    for (unsigned e = beg + t; e < end; e += 256)
        atomicAdd(&hist[vals[e] & 255], 1u);
    __syncthreads();
    int node = (b << 8) + t;
    if (node < n) dout_cnt[node] = hist[t];
}

__global__ void k_invsqrt2(const unsigned* __restrict__ c0, float* __restrict__ i0,
                           const unsigned* __restrict__ c1, float* __restrict__ i1, int n) {
    int i = blockIdx.x * blockDim.x + threadIdx.x;
    if (i < n) {
        i0[i] = 1.0f / sqrtf(fmaxf((float)c0[i], 1.0f));
        i1[i] = 1.0f / sqrtf(fmaxf((float)c1[i], 1.0f));
    }
}

// ---------------- layer 1 (aggregate-first, 4-wide) ----------------

__global__ void k_prescale4(const float* __restrict__ x, const float* __restrict__ dout_is,
                            float* __restrict__ pf4, int n) {
    int i = blockIdx.x * blockDim.x + threadIdx.x;
    if (i >= n) return;
    float s = dout_is[i];
    float4 v = *reinterpret_cast<const float4*>(x + (size_t)i * 4);
    float4 o = {v.x * s, v.y * s, v.z * s, v.w * s};
    *reinterpret_cast<float4*>(pf4 + (size_t)i * 4) = o;
}

__global__ void k_gather4(const float* __restrict__ pf4, const int* __restrict__ csr,
                          const unsigned* __restrict__ row_ptr, const float* __restrict__ din_is,
                          const float* __restrict__ dout_is, float* __restrict__ a4, int n) {
    int i = blockIdx.x * blockDim.x + threadIdx.x;
    if (i >= n) return;
    unsigned beg = row_ptr[i], end = row_ptr[i + 1];
    float4 acc = {0.f, 0.f, 0.f, 0.f};
    unsigned e = beg;
    for (; e + 4 <= end; e += 4) {
        int s0 = csr[e], s1 = csr[e + 1], s2 = csr[e + 2], s3 = csr[e + 3];
        float4 v0 = *reinterpret_cast<const float4*>(pf4 + (size_t)s0 * 4);
        float4 v1 = *reinterpret_cast<const float4*>(pf4 + (size_t)s1 * 4);
        float4 v2 = *reinterpret_cast<const float4*>(pf4 + (size_t)s2 * 4);
        float4 v3 = *reinterpret_cast<const float4*>(pf4 + (size_t)s3 * 4);
        acc.x += (v0.x + v1.x) + (v2.x + v3.x);
        acc.y += (v0.y + v1.y) + (v2.y + v3.y);
        acc.z += (v0.z + v1.z) + (v2.z + v3.z);
        acc.w += (v0.w + v1.w) + (v2.w + v3.w);
    }
    for (; e < end; ++e) {
        int s = csr[e];
        float4 v = *reinterpret_cast<const float4*>(pf4 + (size_t)s * 4);
        acc.x += v.x; acc.y += v.y; acc.z += v.z; acc.w += v.w;
    }
    float sc = din_is[i] * dout_is[i];
    float4 o = {acc.x * sc, acc.y * sc, acc.z * sc, acc.w * sc};
    *reinterpret_cast<float4*>(a4 + (size_t)i * 4) = o;
}

// ---------------- fp16 helpers ----------------

__device__ inline void sth16(__half* p, const float* v) {
    __half2 hh[8];
#pragma unroll
    for (int q = 0; q < 8; ++q) hh[q] = __floats2half2_rn(v[2 * q], v[2 * q + 1]);
    const float4* f = reinterpret_cast<const float4*>(&hh[0]);
    *reinterpret_cast<float4*>(p) = f[0];
    *reinterpret_cast<float4*>(p + 8) = f[1];
}

__device__ inline float2 h2f(unsigned u) {
    __half2 h = *reinterpret_cast<__half2*>(&u);
    return __half22float2(h);
}

// 64-lane bitonic: lane L ends holding the row id with degree-rank L
__device__ inline int degree_rank_row(const unsigned* __restrict__ row_ptr,
                                      int bbase, int lane, int n) {
    int node0 = bbase + lane;
    int deg = 0;
    if (node0 < n) deg = (int)(row_ptr[node0 + 1] - row_ptr[node0]);
    int key = (deg << 8) | lane;
#pragma unroll
    for (int k = 2; k <= 64; k <<= 1) {
#pragma unroll
        for (int j = k >> 1; j >= 1; j >>= 1) {
            int other = __shfl_xor(key, j, 64);
            bool up = ((lane & k) == 0);
            bool lower = ((lane & j) == 0);
            int mn = min(key, other), mx = max(key, other);
            key = (up == lower) ? mn : mx;
        }
    }
    return key & 255;
}

// ---------------- fused layers 1+2 (lane-parallel recompute) ----------------

__device__ inline float4 xp1_cols(float4 av, float ds, float4 wa, float4 wb, float4 wc, float4 wd, float4 bc) {
    float4 r;
    r.x = fmaf(av.x, wa.x, fmaf(av.y, wb.x, fmaf(av.z, wc.x, fmaf(av.w, wd.x, ds * bc.x))));
    r.y = fmaf(av.x, wa.y, fmaf(av.y, wb.y, fmaf(av.z, wc.y, fmaf(av.w, wd.y, ds * bc.y))));
    r.z = fmaf(av.x, wa.z, fmaf(av.y, wb.z, fmaf(av.z, wc.z, fmaf(av.w, wd.z, ds * bc.z))));
    r.w = fmaf(av.x, wa.w, fmaf(av.y, wb.w, fmaf(av.z, wc.w, fmaf(av.w, wd.w, ds * bc.w))));
    r.x = fmaxf(r.x, LRELU_SLOPE * r.x);
    r.y = fmaxf(r.y, LRELU_SLOPE * r.y);
    r.z = fmaxf(r.z, LRELU_SLOPE * r.z);
    r.w = fmaxf(r.w, LRELU_SLOPE * r.w);
    return r;
}

__global__ __launch_bounds__(512) void k_gl12(const float* __restrict__ a4,
                                              const float* __restrict__ dout_v,
                                              const int* __restrict__ csr,
                                              const unsigned* __restrict__ row_ptr,
                                              const float* __restrict__ din_is, const float* __restrict__ dout_is,
                                              const float* __restrict__ W1, const float* __restrict__ b1,
                                              const float* __restrict__ W2, const float* __restrict__ b2,
                                              __half* __restrict__ xh_out, int n) {
    __shared__ float xs[64 * XPAD];  // 33 KB
    const int t = threadIdx.x;
    const int bbase = blockIdx.x * 64;
    const int wave = t >> 6;
    const int lane = t & 63;
    const int half = lane >> 5;
    const int j4 = (lane & 31) * 4;

    float4 wa = *reinterpret_cast<const float4*>(W1 + 0 * 128 + j4);
    float4 wb = *reinterpret_cast<const float4*>(W1 + 1 * 128 + j4);
    float4 wc = *reinterpret_cast<const float4*>(W1 + 2 * 128 + j4);
    float4 wd = *reinterpret_cast<const float4*>(W1 + 3 * 128 + j4);
    float4 bc = *reinterpret_cast<const float4*>(b1 + j4);

#pragma unroll
    for (int sweep = 0; sweep < 4; ++sweep) {
        int r = wave * 2 + half + sweep * 16;
        int node = bbase + r;
        float4 acc = {0.f, 0.f, 0.f, 0.f};
        if (node < n) {
            unsigned beg = row_ptr[node], end = row_ptr[node + 1];
            unsigned e = beg;
            for (; e + 4 <= end; e += 4) {
                int s0 = csr[e + 0], s1 = csr[e + 1], s2 = csr[e + 2], s3 = csr[e + 3];
                float4 a0 = *reinterpret_cast<const float4*>(a4 + (size_t)s0 * 4);
                float4 a1 = *reinterpret_cast<const float4*>(a4 + (size_t)s1 * 4);
                float4 a2 = *reinterpret_cast<const float4*>(a4 + (size_t)s2 * 4);
                float4 a3 = *reinterpret_cast<const float4*>(a4 + (size_t)s3 * 4);
                float d0 = dout_v[s0], d1 = dout_v[s1], d2 = dout_v[s2], d3 = dout_v[s3];
                float4 x0 = xp1_cols(a0, d0, wa, wb, wc, wd, bc);
                float4 x1 = xp1_cols(a1, d1, wa, wb, wc, wd, bc);
                float4 x2 = xp1_cols(a2, d2, wa, wb, wc, wd, bc);
                float4 x3 = xp1_cols(a3, d3, wa, wb, wc, wd, bc);
                acc.x += (x0.x + x1.x) + (x2.x + x3.x);
                acc.y += (x0.y + x1.y) + (x2.y + x3.y);
                acc.z += (x0.z + x1.z) + (x2.z + x3.z);
                acc.w += (x0.w + x1.w) + (x2.w + x3.w);
            }
            for (; e < end; ++e) {
                int s = csr[e];
                float4 av = *reinterpret_cast<const float4*>(a4 + (size_t)s * 4);
                float4 xv = xp1_cols(av, dout_v[s], wa, wb, wc, wd, bc);
                acc.x += xv.x; acc.y += xv.y; acc.z += xv.z; acc.w += xv.w;
            }
            float di = din_is[node];
            acc.x *= di; acc.y *= di; acc.z *= di; acc.w *= di;
        }
        float* d = xs + r * XPAD + j4;
        d[0] = acc.x; d[1] = acc.y; d[2] = acc.z; d[3] = acc.w;
    }
    __syncthreads();

    const int jg = __builtin_amdgcn_readfirstlane(wave) & 7;
    const int j0 = jg * 16;
    const float* Wj = W2 + j0;
    const float* xrow = xs + lane * XPAD;

    float acc[16];
#pragma unroll
    for (int q = 0; q < 16; ++q) acc[q] = 0.f;

#pragma unroll 2
    for (int k = 0; k < 128; k += 4) {
        float x0 = xrow[k + 0];
        float x1 = xrow[k + 1];
        float x2 = xrow[k + 2];
        float x3 = xrow[k + 3];
        const float* w0 = Wj + (size_t)k * 128;
#pragma unroll
        for (int q = 0; q < 16; ++q) {
            acc[q] += x0 * w0[q] + x1 * w0[128 + q] + x2 * w0[256 + q] + x3 * w0[384 + q];
        }
    }

    int node = bbase + lane;
    if (node < n) {
        float s = dout_is[node];
        float v[16];
#pragma unroll
        for (int q = 0; q < 16; ++q) {
            float u = acc[q] + b2[j0 + q];
            u = fmaxf(u, LRELU_SLOPE * u);
            v[q] = u * s;
        }
        sth16(xh_out + (size_t)node * 128 + j0, v);
    }
}

// -------- XCD-affine column-sliced gather: g = din * sum_in(xh), fp16 --------
// slice = blockIdx&7 (-> XCD via round-robin heuristic): each XCD touches
// only N x 32B of xh (3.2MB, L2-resident). 8 lanes/node (2 cols each),
// degree-rank grouping keeps the 8 groups of a wave at equal degree.

__global__ __launch_bounds__(256) void k_gcol(const __half* __restrict__ xh, const int* __restrict__ csr,
                                              const unsigned* __restrict__ row_ptr,
                                              const float* __restrict__ din_is,
                                              __half* __restrict__ g, int n) {
    const int slice = blockIdx.x & 7;
    const int bbase = (blockIdx.x >> 3) * 64;
    const int t = threadIdx.x;
    const int wave = t >> 6;        // 0..3
    const int lane = t & 63;
    const int grp = lane >> 3;      // 0..7 node-groups per wave
    const int li = lane & 7;        // 2 cols per lane
    const int c0 = slice * 16 + li * 2;

    const int Lr = degree_rank_row(row_ptr, bbase, lane, n);

#pragma unroll
    for (int sweep = 0; sweep < 2; ++sweep) {
        int rank = sweep * 32 + wave * 8 + grp;
        int r = __shfl(Lr, rank, 64);
        int node = bbase + r;
        float a0 = 0.f, a1 = 0.f;
        float b0 = 0.f, b1 = 0.f;
        if (node < n) {
            unsigned beg = row_ptr[node], end = row_ptr[node + 1];
            unsigned e = beg;
            for (; e + 8 <= end; e += 8) {
                int s0 = csr[e + 0], s1 = csr[e + 1], s2 = csr[e + 2], s3 = csr[e + 3];
                int s4 = csr[e + 4], s5 = csr[e + 5], s6 = csr[e + 6], s7 = csr[e + 7];
                unsigned u0 = *reinterpret_cast<const unsigned*>(xh + (size_t)s0 * 128 + c0);
                unsigned u1 = *reinterpret_cast<const unsigned*>(xh + (size_t)s1 * 128 + c0);
                unsigned u2 = *reinterpret_cast<const unsigned*>(xh + (size_t)s2 * 128 + c0);
                unsigned u3 = *reinterpret_cast<const unsigned*>(xh + (size_t)s3 * 128 + c0);
                unsigned u4 = *reinterpret_cast<const unsigned*>(xh + (size_t)s4 * 128 + c0);
                unsigned u5 = *reinterpret_cast<const unsigned*>(xh + (size_t)s5 * 128 + c0);
                unsigned u6 = *reinterpret_cast<const unsigned*>(xh + (size_t)s6 * 128 + c0);
                unsigned u7 = *reinterpret_cast<const unsigned*>(xh + (size_t)s7 * 128 + c0);
                float2 f0 = h2f(u0), f1 = h2f(u1), f2 = h2f(u2), f3 = h2f(u3);
                float2 f4 = h2f(u4), f5 = h2f(u5), f6 = h2f(u6), f7 = h2f(u7);
                a0 += (f0.x + f1.x) + (f2.x + f3.x);
                a1 += (f0.y + f1.y) + (f2.y + f3.y);
                b0 += (f4.x + f5.x) + (f6.x + f7.x);
                b1 += (f4.y + f5.y) + (f6.y + f7.y);
            }
            for (; e < end; ++e) {
                int s = csr[e];
                float2 f = h2f(*reinterpret_cast<const unsigned*>(xh + (size_t)s * 128 + c0));
                a0 += f.x; a1 += f.y;
            }
            float di = din_is[node];
            a0 = (a0 + b0) * di;
            a1 = (a1 + b1) * di;
            __half2 o = __floats2half2_rn(a0, a1);
            *reinterpret_cast<__half2*>(g + (size_t)node * 128 + c0) = o;
        }
    }
}

// -------- GEMM from fp16 g (streaming read) -> epilogue -> fp16 xp --------

__global__ __launch_bounds__(512) void k_lin128g(const __half* __restrict__ g,
                                                 const float* __restrict__ dout_is,
                                                 const float* __restrict__ W, const float* __restrict__ b,
                                                 __half* __restrict__ xh_out, int n) {
    __shared__ float xs[64 * XPAD];
    const int t = threadIdx.x;
    const int bbase = blockIdx.x * 64;
    // stage: thread t -> node t>>3, 16 cols at (t&7)*16
    {
        int node = bbase + (t >> 3);
        int c = (t & 7) * 16;
        float v[16];
        if (node < n) {
            uint4 u0 = *reinterpret_cast<const uint4*>(g + (size_t)node * 128 + c);
            uint4 u1 = *reinterpret_cast<const uint4*>(g + (size_t)node * 128 + c + 8);
            const unsigned* uu = reinterpret_cast<const unsigned*>(&u0);
#pragma unroll
            for (int q = 0; q < 4; ++q) { float2 f = h2f(uu[q]); v[2 * q] = f.x; v[2 * q + 1] = f.y; }
            uu = reinterpret_cast<const unsigned*>(&u1);
#pragma unroll
            for (int q = 0; q < 4; ++q) { float2 f = h2f(uu[q]); v[8 + 2 * q] = f.x; v[9 + 2 * q] = f.y; }
        } else {
#pragma unroll
            for (int q = 0; q < 16; ++q) v[q] = 0.f;
        }
        float* d = xs + (t >> 3) * XPAD + c;
#pragma unroll
        for (int q = 0; q < 16; ++q) d[q] = v[q];
    }
    __syncthreads();

    const int wave = t >> 6;
    const int lane = t & 63;
    const int jg = __builtin_amdgcn_readfirstlane(wave) & 7;
    const int j0 = jg * 16;
    const float* Wj = W + j0;
    const float* xrow = xs + lane * XPAD;

    float acc[16];
#pragma unroll
    for (int q = 0; q < 16; ++q) acc[q] = 0.f;

#pragma unroll 2
    for (int k = 0; k < 128; k += 4) {
        float x0 = xrow[k + 0];
        float x1 = xrow[k + 1];
        float x2 = xrow[k + 2];
        float x3 = xrow[k + 3];
        const float* w0 = Wj + (size_t)k * 128;
#pragma unroll
        for (int q = 0; q < 16; ++q) {
            acc[q] += x0 * w0[q] + x1 * w0[128 + q] + x2 * w0[256 + q] + x3 * w0[384 + q];
        }
    }

    int node = bbase + lane;
    if (node < n) {
        float s = dout_is[node];
        float v[16];
#pragma unroll
        for (int q = 0; q < 16; ++q) {
            float u = acc[q] + b[j0 + q];
            u = fmaxf(u, LRELU_SLOPE * u);
            v[q] = u * s;
        }
        sth16(xh_out + (size_t)node * 128 + j0, v);
    }
}

// -------- GEMM from fp16 g + fused W5 epilogue -> h5 (layers 4+5) --------

__global__ __launch_bounds__(512) void k_lin128g5(const __half* __restrict__ g,
                                                  const float* __restrict__ dout_is,
                                                  const float* __restrict__ W, const float* __restrict__ b,
                                                  const float* __restrict__ W5,
                                                  float* __restrict__ h5, int n) {
    __shared__ float xs[64 * XPAD];
    const int t = threadIdx.x;
    const int bbase = blockIdx.x * 64;
    {
        int node = bbase + (t >> 3);
        int c = (t & 7) * 16;
        float v[16];
        if (node < n) {
            uint4 u0 = *reinterpret_cast<const uint4*>(g + (size_t)node * 128 + c);
            uint4 u1 = *reinterpret_cast<const uint4*>(g + (size_t)node * 128 + c + 8);
            const unsigned* uu = reinterpret_cast<const unsigned*>(&u0);
#pragma unroll
            for (int q = 0; q < 4; ++q) { float2 f = h2f(uu[q]); v[2 * q] = f.x; v[2 * q + 1] = f.y; }
            uu = reinterpret_cast<const unsigned*>(&u1);
#pragma unroll
            for (int q = 0; q < 4; ++q) { float2 f = h2f(uu[q]); v[8 + 2 * q] = f.x; v[9 + 2 * q] = f.y; }
        } else {
#pragma unroll
            for (int q = 0; q < 16; ++q) v[q] = 0.f;
        }
        float* d = xs + (t >> 3) * XPAD + c;
#pragma unroll
        for (int q = 0; q < 16; ++q) d[q] = v[q];
    }
    __syncthreads();

    const int wave = t >> 6;
    const int lane = t & 63;
    const int jg = __builtin_amdgcn_readfirstlane(wave) & 7;
    const int j0 = jg * 16;
    const float* Wj = W + j0;
    const float* xrow = xs + lane * XPAD;

    float acc[16];
#pragma unroll
    for (int q = 0; q < 16; ++q) acc[q] = 0.f;

#pragma unroll 2
    for (int k = 0; k < 128; k += 4) {
        float x0 = xrow[k + 0];
        float x1 = xrow[k + 1];
        float x2 = xrow[k + 2];
        float x3 = xrow[k + 3];
        const float* w0 = Wj + (size_t)k * 128;
#pragma unroll
        for (int q = 0; q < 16; ++q) {
            acc[q] += x0 * w0[q] + x1 * w0[128 + q] + x2 * w0[256 + q] + x3 * w0[384 + q];
        }
    }

    // epilogue: xp4 cols -> partial (xp4 @ W5) per (node, wave); LDS reduce
    float s = (bbase + lane < n) ? dout_is[bbase + lane] : 0.f;
    float p0 = 0.f, p1 = 0.f, p2 = 0.f;
#pragma unroll
    for (int q = 0; q < 16; ++q) {
        float u = acc[q] + b[j0 + q];
        u = fmaxf(u, LRELU_SLOPE * u);
        u *= s;
        const float* w5r = W5 + (size_t)(j0 + q) * 3;
        p0 = fmaf(u, w5r[0], p0);
        p1 = fmaf(u, w5r[1], p1);
        p2 = fmaf(u, w5r[2], p2);
    }
    __syncthreads();
    float* red = xs;  // [node(64)][wave(8)][3]
    red[lane * 24 + wave * 3 + 0] = p0;
    red[lane * 24 + wave * 3 + 1] = p1;
    red[lane * 24 + wave * 3 + 2] = p2;
    __syncthreads();
    if (t < 64) {
        int node = bbase + t;
        if (node < n) {
            float a0 = 0.f, a1 = 0.f, a2 = 0.f;
#pragma unroll
            for (int w = 0; w < 8; ++w) {
                a0 += red[t * 24 + w * 3 + 0];
                a1 += red[t * 24 + w * 3 + 1];
                a2 += red[t * 24 + w * 3 + 2];
            }
            h5[(size_t)node * 3 + 0] = a0;
            h5[(size_t)node * 3 + 1] = a1;
            h5[(size_t)node * 3 + 2] = a2;
        }
    }
}

// ---------------- final 3-wide gather ----------------

__global__ void k_gather3(const float* __restrict__ h, const int* __restrict__ csr,
                          const unsigned* __restrict__ row_ptr, const float* __restrict__ din_is,
                          const float* __restrict__ b, float* __restrict__ out, int n) {
    int i = blockIdx.x * blockDim.x + threadIdx.x;
    if (i >= n) return;
    unsigned beg = row_ptr[i], end = row_ptr[i + 1];
    float a0 = 0.f, a1 = 0.f, a2 = 0.f;
    for (unsigned e = beg; e < end; ++e) {
        int s = csr[e];
        a0 += h[(size_t)s * 3 + 0];
        a1 += h[(size_t)s * 3 + 1];
        a2 += h[(size_t)s * 3 + 2];
    }
    float di = din_is[i];
    out[(size_t)i * 3 + 0] = a0 * di + b[0];
    out[(size_t)i * 3 + 1] = a1 * di + b[1];
    out[(size_t)i * 3 + 2] = a2 * di + b[2];
}

// ---------------- launch ----------------

extern "C" void kernel_launch(void* const* d_in, const int* in_sizes, int n_in,
                              void* d_out, int out_size, void* d_ws, size_t ws_size,
                              hipStream_t stream) {
    const float* features = (const float*)d_in[0];
    const int* esrc = (const int*)d_in[1];
    const int* edst = (const int*)d_in[2];
    const float* W1 = (const float*)d_in[3];  const float* b1 = (const float*)d_in[4];
    const float* W2 = (const float*)d_in[5];  const float* b2 = (const float*)d_in[6];
    const float* W3 = (const float*)d_in[7];  const float* b3 = (const float*)d_in[8];
    const float* W4 = (const float*)d_in[9];  const float* b4 = (const float*)d_in[10];
    const float* W5 = (const float*)d_in[11]; const float* b5 = (const float*)d_in[12];

    const int N = in_sizes[0] / 4;
    const int E = in_sizes[1];
    const int nbuck = (N + 255) / 256;
    const int NPB = 256;

    size_t off = 0;
    auto carve = [&](size_t bytes) -> void* {
        void* p = (char*)d_ws + off;
        off = (off + bytes + 255) & ~(size_t)255;
        return p;
    };
    char*     scratch   = (char*)carve((size_t)E * 12 + 256);   // pairs + srcbuf
    float*    Bp        = (float*)carve((size_t)N * 8 * 4);     // pf4 + a4
    __half*   xh2       = (__half*)carve((size_t)N * 128 * 2);
    __half*   xh3       = (__half*)carve((size_t)N * 128 * 2);
    __half*   gbuf      = (__half*)carve((size_t)N * 128 * 2);
    int*      csr       = (int*)carve((size_t)E * 4);
    unsigned* row_ptr   = (unsigned*)carve((size_t)(N + 1) * 4);
    unsigned* dout_cnt  = (unsigned*)carve((size_t)N * 4);
    unsigned* din_cnt   = (unsigned*)carve((size_t)N * 4);
    float*    dout_is   = (float*)carve((size_t)N * 4);
    float*    din_is    = (float*)carve((size_t)N * 4);
    unsigned* gHistD    = (unsigned*)carve((size_t)MAXBUCK * 4);
    unsigned* gHistS    = (unsigned*)carve((size_t)MAXBUCK * 4);
    unsigned* bstartD   = (unsigned*)carve((size_t)(MAXBUCK + 1) * 4);
    unsigned* bstartS   = (unsigned*)carve((size_t)(MAXBUCK + 1) * 4);
    unsigned* blockBaseD = (unsigned*)carve((size_t)NPB * nbuck * 4);
    unsigned* blockBaseS = (unsigned*)carve((size_t)NPB * nbuck * 4);
    float*    h5        = (float*)carve((size_t)N * 3 * 4);
    (void)ws_size;
    int2* pairs  = (int2*)scratch;
    int*  srcbuf = (int*)(scratch + (size_t)E * 8);
    float* pf4 = Bp;
    float* a4  = Bp + (size_t)N * 4;

    hipMemsetAsync(gHistD, 0, (size_t)MAXBUCK * 4, stream);
    hipMemsetAsync(gHistS, 0, (size_t)MAXBUCK * 4, stream);

    // ---- bucket-partition preprocessing ----
    k_part_hist2<<<NPB, 256, 0, stream>>>(esrc, edst, E, nbuck, gHistS, gHistD, blockBaseS, blockBaseD);
    k_part_scan<<<1, 512, 0, stream>>>(gHistD, nbuck, bstartD, row_ptr + N, (unsigned)E);
    k_part_scan<<<1, 512, 0, stream>>>(gHistS, nbuck, bstartS, (unsigned*)nullptr, 0u);
    k_part_scatter_both<<<NPB, 256, 0, stream>>>(esrc, edst, E, nbuck, bstartS, bstartD,
                                                 blockBaseS, blockBaseD, pairs, srcbuf);
    k_bucket_csr<<<nbuck, 256, 0, stream>>>(pairs, bstartD, row_ptr, din_cnt, csr, N);
    k_bucket_cnt<<<nbuck, 256, 0, stream>>>(srcbuf, bstartS, dout_cnt, N);
    k_invsqrt2<<<(N + 255) / 256, 256, 0, stream>>>(dout_cnt, dout_is, din_cnt, din_is, N);

    // ---- layer 1 prep: 4-wide prescale + aggregate ----
    k_prescale4<<<(N + 255) / 256, 256, 0, stream>>>(features, dout_is, pf4, N);
    k_gather4<<<(N + 255) / 256, 256, 0, stream>>>(pf4, csr, row_ptr, din_is, dout_is, a4, N);

    // ---- layers 1+2 fused -> xh2 ----
    int nTiles = (N + 63) / 64;
    k_gl12<<<nTiles, 512, 0, stream>>>(a4, dout_is, csr, row_ptr, din_is, dout_is, W1, b1, W2, b2, xh2, N);

    // ---- layer 3: col-sliced gather + GEMM ----
    k_gcol<<<nTiles * 8, 256, 0, stream>>>(xh2, csr, row_ptr, din_is, gbuf, N);
    k_lin128g<<<nTiles, 512, 0, stream>>>(gbuf, dout_is, W3, b3, xh3, N);

    // ---- layers 4+5: col-sliced gather + GEMM + W5 epilogue ----
    k_gcol<<<nTiles * 8, 256, 0, stream>>>(xh3, csr, row_ptr, din_is, gbuf, N);
    k_lin128g5<<<nTiles, 512, 0, stream>>>(gbuf, dout_is, W4, b4, W5, h5, N);

    // ---- final gather ----
    k_gather3<<<(N + 255) / 256, 256, 0, stream>>>(h5, csr, row_ptr, din_is, b5, (float*)d_out, N);
}

// Round 14
// 434.632 us; speedup vs baseline: 1.6350x; 1.6350x over previous
//
#include <hip/hip_runtime.h>
#include <hip/hip_fp16.h>
#include <math.h>

// GraphConv x5 (DGL norm='both') on MI355X.  (R14 = R10 revert, best-known 437us)
// - CSR via LDS-binned two-pass bucket partition (no 3.2M-atomic storms).
// - Layer 1 algebra: aggregate 4-wide features first; layer-2 gather
//   recomputes xp1 per edge from L2-resident a4 (kills the 377MB floor).
// - Layers 3/4 gather fp16 rows (halves compulsory L2-miss bytes), paired-
//   edge dwordx4 loads (2 edges per 32-lane group), shfl_xor(16) merge.
// - Layer 5 fused into L4 epilogue (LDS cross-wave reduce -> h5).
// Falsified alternatives (counters): src-sorted CSR (R6: FETCH unchanged),
// scalar/SMEM gather (R11: MLP collapse), 4-slot gather (R12: -3%),
// XCD column slicing (R13: FETCH 652MB, 3.7x over-fetch).

#define LRELU_SLOPE 0.01f
#define XPAD 129     // 128+1: LDS bank (lane+k)%32 -> 2-way on wave64 = free
#define MAXBUCK 512  // supports N <= 131072

// ---------------- bucket-partition preprocessing ----------------

__device__ inline void chunk_range(int E, int nchunks, int cid, int& lo, int& hi) {
    int chunk = (E + nchunks - 1) / nchunks;
    lo = cid * chunk;
    hi = min(E, lo + chunk);
}

__global__ __launch_bounds__(256) void k_part_hist2(const int* __restrict__ src, const int* __restrict__ dst,
                                                    int E, int nbuck,
                                                    unsigned* __restrict__ gHistS, unsigned* __restrict__ gHistD,
                                                    unsigned* __restrict__ blockBaseS, unsigned* __restrict__ blockBaseD) {
    __shared__ unsigned hs[MAXBUCK];
    __shared__ unsigned hd[MAXBUCK];
    for (int i = threadIdx.x; i < nbuck; i += 256) { hs[i] = 0u; hd[i] = 0u; }
    __syncthreads();
    int lo, hi;
    chunk_range(E, gridDim.x, blockIdx.x, lo, hi);
    for (int e = lo + threadIdx.x; e < hi; e += 256) {
        atomicAdd(&hs[src[e] >> 8], 1u);
        atomicAdd(&hd[dst[e] >> 8], 1u);
    }
    __syncthreads();
    for (int i = threadIdx.x; i < nbuck; i += 256) {
        blockBaseS[(size_t)blockIdx.x * nbuck + i] = atomicAdd(&gHistS[i], hs[i]);
        blockBaseD[(size_t)blockIdx.x * nbuck + i] = atomicAdd(&gHistD[i], hd[i]);
    }
}

// fused dual scan: bucketStartD/S from gHistD/S; row_ptr[N]=E
__global__ __launch_bounds__(512) void k_part_scan2(const unsigned* __restrict__ gHistD,
                                                    const unsigned* __restrict__ gHistS, int nbuck,
                                                    unsigned* __restrict__ bstartD, unsigned* __restrict__ bstartS,
                                                    unsigned* __restrict__ row_ptr_last, unsigned Eval) {
    __shared__ unsigned sd[MAXBUCK];
    __shared__ unsigned ss[MAXBUCK];
    int t = threadIdx.x;
    sd[t] = (t < nbuck) ? gHistD[t] : 0u;
    ss[t] = (t < nbuck) ? gHistS[t] : 0u;
    __syncthreads();
    for (int off = 1; off < MAXBUCK; off <<= 1) {
        unsigned vd = (t >= off) ? sd[t - off] : 0u;
        unsigned vs = (t >= off) ? ss[t - off] : 0u;
        __syncthreads();
        sd[t] += vd;
        ss[t] += vs;
        __syncthreads();
    }
    if (t <= nbuck) {
        bstartD[t] = (t == 0) ? 0u : sd[t - 1];
        bstartS[t] = (t == 0) ? 0u : ss[t - 1];
    }
    if (t == 0) *row_ptr_last = Eval;
}

__global__ __launch_bounds__(256) void k_part_scatter_both(const int* __restrict__ src, const int* __restrict__ dst,
                                                           int E, int nbuck,
                                                           const unsigned* __restrict__ bstartS,
                                                           const unsigned* __restrict__ bstartD,
                                                           const unsigned* __restrict__ blockBaseS,
                                                           const unsigned* __restrict__ blockBaseD,
                                                           int2* __restrict__ pairs, int* __restrict__ srcbuf) {
    __shared__ unsigned curS[MAXBUCK];
    __shared__ unsigned curD[MAXBUCK];
    for (int i = threadIdx.x; i < nbuck; i += 256) {
        curS[i] = bstartS[i] + blockBaseS[(size_t)blockIdx.x * nbuck + i];
        curD[i] = bstartD[i] + blockBaseD[(size_t)blockIdx.x * nbuck + i];
    }
    __syncthreads();
    int lo, hi;
    chunk_range(E, gridDim.x, blockIdx.x, lo, hi);
    for (int e = lo + threadIdx.x; e < hi; e += 256) {
        int s = src[e], d = dst[e];
        unsigned posD = atomicAdd(&curD[d >> 8], 1u);
        pairs[posD] = make_int2(s, d);
        unsigned posS = atomicAdd(&curS[s >> 8], 1u);
        srcbuf[posS] = s;
    }
}

__global__ __launch_bounds__(256) void k_bucket_csr(const int2* __restrict__ pairs,
                                                    const unsigned* __restrict__ bucketStart,
                                                    unsigned* __restrict__ row_ptr,
                                                    unsigned* __restrict__ din_cnt,
                                                    int* __restrict__ csr, int n) {
    __shared__ unsigned hist[256];
    __shared__ unsigned scanw[256];
    __shared__ unsigned cur[256];
    int b = blockIdx.x, t = threadIdx.x;
    unsigned beg = bucketStart[b], end = bucketStart[b + 1];
    hist[t] = 0u;
    __syncthreads();
    for (unsigned e = beg + t; e < end; e += 256)
        atomicAdd(&hist[pairs[e].y & 255], 1u);
    __syncthreads();
    scanw[t] = hist[t];
    __syncthreads();
    for (int off = 1; off < 256; off <<= 1) {
        unsigned u = (t >= off) ? scanw[t - off] : 0u;
        __syncthreads();
        scanw[t] += u;
        __syncthreads();
    }
    unsigned excl = scanw[t] - hist[t];
    int node = (b << 8) + t;
    if (node < n) {
        row_ptr[node] = beg + excl;
        din_cnt[node] = hist[t];
    }
    cur[t] = excl;
    __syncthreads();
    for (unsigned e = beg + t; e < end; e += 256) {
        int2 p = pairs[e];
        unsigned pos = beg + atomicAdd(&cur[p.y & 255], 1u);
        csr[pos] = p.x;
    }
}

__global__ __launch_bounds__(256) void k_bucket_cnt(const int* __restrict__ vals,
                                                    const unsigned* __restrict__ bucketStart,
                                                    unsigned* __restrict__ dout_cnt, int n) {
    __shared__ unsigned hist[256];
    int b = blockIdx.x, t = threadIdx.x;
    unsigned beg = bucketStart[b], end = bucketStart[b + 1];
    hist[t] = 0u;
    __syncthreads();
    for (unsigned e = beg + t; e < end; e += 256)
        atomicAdd(&hist[vals[e] & 255], 1u);
    __syncthreads();
    int node = (b << 8) + t;
    if (node < n) dout_cnt[node] = hist[t];
}

__global__ void k_invsqrt2(const unsigned* __restrict__ c0, float* __restrict__ i0,
                           const unsigned* __restrict__ c1, float* __restrict__ i1, int n) {
    int i = blockIdx.x * blockDim.x + threadIdx.x;
    if (i < n) {
        i0[i] = 1.0f / sqrtf(fmaxf((float)c0[i], 1.0f));
        i1[i] = 1.0f / sqrtf(fmaxf((float)c1[i], 1.0f));
    }
}

// ---------------- layer 1 (aggregate-first, 4-wide) ----------------

__global__ void k_prescale4(const float* __restrict__ x, const float* __restrict__ dout_is,
                            float* __restrict__ pf4, int n) {
    int i = blockIdx.x * blockDim.x + threadIdx.x;
    if (i >= n) return;
    float s = dout_is[i];
    float4 v = *reinterpret_cast<const float4*>(x + (size_t)i * 4);
    float4 o = {v.x * s, v.y * s, v.z * s, v.w * s};
    *reinterpret_cast<float4*>(pf4 + (size_t)i * 4) = o;
}

__global__ void k_gather4(const float* __restrict__ pf4, const int* __restrict__ csr,
                          const unsigned* __restrict__ row_ptr, const float* __restrict__ din_is,
                          const float* __restrict__ dout_is, float* __restrict__ a4, int n) {
    int i = blockIdx.x * blockDim.x + threadIdx.x;
    if (i >= n) return;
    unsigned beg = row_ptr[i], end = row_ptr[i + 1];
    float4 acc = {0.f, 0.f, 0.f, 0.f};
    unsigned e = beg;
    for (; e + 4 <= end; e += 4) {
        int s0 = csr[e], s1 = csr[e + 1], s2 = csr[e + 2], s3 = csr[e + 3];
        float4 v0 = *reinterpret_cast<const float4*>(pf4 + (size_t)s0 * 4);
        float4 v1 = *reinterpret_cast<const float4*>(pf4 + (size_t)s1 * 4);
        float4 v2 = *reinterpret_cast<const float4*>(pf4 + (size_t)s2 * 4);
        float4 v3 = *reinterpret_cast<const float4*>(pf4 + (size_t)s3 * 4);
        acc.x += (v0.x + v1.x) + (v2.x + v3.x);
        acc.y += (v0.y + v1.y) + (v2.y + v3.y);
        acc.z += (v0.z + v1.z) + (v2.z + v3.z);
        acc.w += (v0.w + v1.w) + (v2.w + v3.w);
    }
    for (; e < end; ++e) {
        int s = csr[e];
        float4 v = *reinterpret_cast<const float4*>(pf4 + (size_t)s * 4);
        acc.x += v.x; acc.y += v.y; acc.z += v.z; acc.w += v.w;
    }
    float sc = din_is[i] * dout_is[i];
    float4 o = {acc.x * sc, acc.y * sc, acc.z * sc, acc.w * sc};
    *reinterpret_cast<float4*>(a4 + (size_t)i * 4) = o;
}

// ---------------- fp16 helpers ----------------

__device__ inline void sth16(__half* p, const float* v) {
    __half2 hh[8];
#pragma unroll
    for (int q = 0; q < 8; ++q) hh[q] = __floats2half2_rn(v[2 * q], v[2 * q + 1]);
    const float4* f = reinterpret_cast<const float4*>(&hh[0]);
    *reinterpret_cast<float4*>(p) = f[0];
    *reinterpret_cast<float4*>(p + 8) = f[1];
}

__device__ inline void acc8(float* acc, uint4 u) {
    const __half2* h = reinterpret_cast<const __half2*>(&u);
#pragma unroll
    for (int q = 0; q < 4; ++q) {
        float2 f = __half22float2(h[q]);
        acc[2 * q] += f.x;
        acc[2 * q + 1] += f.y;
    }
}

// ---------------- fused layers 1+2 (lane-parallel per-edge recompute) ----------------

__device__ inline float4 xp1_cols(float4 av, float ds, float4 wa, float4 wb, float4 wc, float4 wd, float4 bc) {
    float4 r;
    r.x = fmaf(av.x, wa.x, fmaf(av.y, wb.x, fmaf(av.z, wc.x, fmaf(av.w, wd.x, ds * bc.x))));
    r.y = fmaf(av.x, wa.y, fmaf(av.y, wb.y, fmaf(av.z, wc.y, fmaf(av.w, wd.y, ds * bc.y))));
    r.z = fmaf(av.x, wa.z, fmaf(av.y, wb.z, fmaf(av.z, wc.z, fmaf(av.w, wd.z, ds * bc.z))));
    r.w = fmaf(av.x, wa.w, fmaf(av.y, wb.w, fmaf(av.z, wc.w, fmaf(av.w, wd.w, ds * bc.w))));
    r.x = fmaxf(r.x, LRELU_SLOPE * r.x);
    r.y = fmaxf(r.y, LRELU_SLOPE * r.y);
    r.z = fmaxf(r.z, LRELU_SLOPE * r.z);
    r.w = fmaxf(r.w, LRELU_SLOPE * r.w);
    return r;
}

__global__ __launch_bounds__(512) void k_gl12(const float* __restrict__ a4,
                                              const float* __restrict__ dout_v,
                                              const int* __restrict__ csr,
                                              const unsigned* __restrict__ row_ptr,
                                              const float* __restrict__ din_is, const float* __restrict__ dout_is,
                                              const float* __restrict__ W1, const float* __restrict__ b1,
                                              const float* __restrict__ W2, const float* __restrict__ b2,
                                              __half* __restrict__ xh_out, int n) {
    __shared__ float xs[64 * XPAD];  // 33 KB
    const int t = threadIdx.x;
    const int bbase = blockIdx.x * 64;
    const int wave = t >> 6;
    const int lane = t & 63;
    const int half = lane >> 5;
    const int j4 = (lane & 31) * 4;

    float4 wa = *reinterpret_cast<const float4*>(W1 + 0 * 128 + j4);
    float4 wb = *reinterpret_cast<const float4*>(W1 + 1 * 128 + j4);
    float4 wc = *reinterpret_cast<const float4*>(W1 + 2 * 128 + j4);
    float4 wd = *reinterpret_cast<const float4*>(W1 + 3 * 128 + j4);
    float4 bc = *reinterpret_cast<const float4*>(b1 + j4);

#pragma unroll
    for (int sweep = 0; sweep < 4; ++sweep) {
        int r = wave * 2 + half + sweep * 16;
        int node = bbase + r;
        float4 acc = {0.f, 0.f, 0.f, 0.f};
        if (node < n) {
            unsigned beg = row_ptr[node], end = row_ptr[node + 1];
            unsigned e = beg;
            for (; e + 4 <= end; e += 4) {
                int s0 = csr[e + 0], s1 = csr[e + 1], s2 = csr[e + 2], s3 = csr[e + 3];
                float4 a0 = *reinterpret_cast<const float4*>(a4 + (size_t)s0 * 4);
                float4 a1 = *reinterpret_cast<const float4*>(a4 + (size_t)s1 * 4);
                float4 a2 = *reinterpret_cast<const float4*>(a4 + (size_t)s2 * 4);
                float4 a3 = *reinterpret_cast<const float4*>(a4 + (size_t)s3 * 4);
                float d0 = dout_v[s0], d1 = dout_v[s1], d2 = dout_v[s2], d3 = dout_v[s3];
                float4 x0 = xp1_cols(a0, d0, wa, wb, wc, wd, bc);
                float4 x1 = xp1_cols(a1, d1, wa, wb, wc, wd, bc);
                float4 x2 = xp1_cols(a2, d2, wa, wb, wc, wd, bc);
                float4 x3 = xp1_cols(a3, d3, wa, wb, wc, wd, bc);
                acc.x += (x0.x + x1.x) + (x2.x + x3.x);
                acc.y += (x0.y + x1.y) + (x2.y + x3.y);
                acc.z += (x0.z + x1.z) + (x2.z + x3.z);
                acc.w += (x0.w + x1.w) + (x2.w + x3.w);
            }
            for (; e < end; ++e) {
                int s = csr[e];
                float4 av = *reinterpret_cast<const float4*>(a4 + (size_t)s * 4);
                float4 xv = xp1_cols(av, dout_v[s], wa, wb, wc, wd, bc);
                acc.x += xv.x; acc.y += xv.y; acc.z += xv.z; acc.w += xv.w;
            }
            float di = din_is[node];
            acc.x *= di; acc.y *= di; acc.z *= di; acc.w *= di;
        }
        float* d = xs + r * XPAD + j4;
        d[0] = acc.x; d[1] = acc.y; d[2] = acc.z; d[3] = acc.w;
    }
    __syncthreads();

    const int jg = __builtin_amdgcn_readfirstlane(wave) & 7;
    const int j0 = jg * 16;
    const float* Wj = W2 + j0;
    const float* xrow = xs + lane * XPAD;

    float acc[16];
#pragma unroll
    for (int q = 0; q < 16; ++q) acc[q] = 0.f;

#pragma unroll 2
    for (int k = 0; k < 128; k += 4) {
        float x0 = xrow[k + 0];
        float x1 = xrow[k + 1];
        float x2 = xrow[k + 2];
        float x3 = xrow[k + 3];
        const float* w0 = Wj + (size_t)k * 128;
#pragma unroll
        for (int q = 0; q < 16; ++q) {
            acc[q] += x0 * w0[q] + x1 * w0[128 + q] + x2 * w0[256 + q] + x3 * w0[384 + q];
        }
    }

    int node = bbase + lane;
    if (node < n) {
        float s = dout_is[node];
        float v[16];
#pragma unroll
        for (int q = 0; q < 16; ++q) {
            float u = acc[q] + b2[j0 + q];
            u = fmaxf(u, LRELU_SLOPE * u);
            v[q] = u * s;
        }
        sth16(xh_out + (size_t)node * 128 + j0, v);
    }
}

// ---------------- fp16 gather macro (paired-edge dwordx4) ----------------
// lanes: half=lane>>5 (node), sub=(lane>>4)&1 (edge slot), c8=(lane&15)*8.

#define GATHER_FP16_TILE(XH)                                                         \
    for (int sweep = 0; sweep < 4; ++sweep) {                                        \
        int r = wave * 2 + half + sweep * 16;                                        \
        int node = bbase + r;                                                        \
        float acc[8];                                                                \
        _Pragma("unroll") for (int q = 0; q < 8; ++q) acc[q] = 0.f;                  \
        float di = 0.f;                                                              \
        if (node < n) {                                                              \
            unsigned beg = row_ptr[node], end = row_ptr[node + 1];                   \
            unsigned e = beg;                                                        \
            for (; e + 8 <= end; e += 8) {                                           \
                int s0 = csr[e + 0 + sub];                                           \
                int s1 = csr[e + 2 + sub];                                           \
                int s2 = csr[e + 4 + sub];                                           \
                int s3 = csr[e + 6 + sub];                                           \
                uint4 u0 = *reinterpret_cast<const uint4*>(XH + (size_t)s0 * 128 + c8); \
                uint4 u1 = *reinterpret_cast<const uint4*>(XH + (size_t)s1 * 128 + c8); \
                uint4 u2 = *reinterpret_cast<const uint4*>(XH + (size_t)s2 * 128 + c8); \
                uint4 u3 = *reinterpret_cast<const uint4*>(XH + (size_t)s3 * 128 + c8); \
                acc8(acc, u0); acc8(acc, u1); acc8(acc, u2); acc8(acc, u3);          \
            }                                                                        \
            for (; e + 2 <= end; e += 2) {                                           \
                int s = csr[e + sub];                                                \
                acc8(acc, *reinterpret_cast<const uint4*>(XH + (size_t)s * 128 + c8)); \
            }                                                                        \
            if (e < end && sub == 0) {                                               \
                int s = csr[e];                                                      \
                acc8(acc, *reinterpret_cast<const uint4*>(XH + (size_t)s * 128 + c8)); \
            }                                                                        \
            di = din_is[node];                                                       \
        }                                                                            \
        _Pragma("unroll") for (int q = 0; q < 8; ++q)                                \
            acc[q] += __shfl_xor(acc[q], 16, 64);                                    \
        if (sub == 0) {                                                              \
            float* d = xs + r * XPAD + c8;                                           \
            _Pragma("unroll") for (int q = 0; q < 8; ++q) d[q] = acc[q] * di;        \
        }                                                                            \
    }

// ---------------- layer 3: fp16 gather -> GEMM -> fp16 out ----------------

__global__ __launch_bounds__(512) void k_gl128h(const __half* __restrict__ xh, const int* __restrict__ csr,
                                                const unsigned* __restrict__ row_ptr,
                                                const float* __restrict__ din_is, const float* __restrict__ dout_is,
                                                const float* __restrict__ W, const float* __restrict__ b,
                                                __half* __restrict__ xh_out, int n) {
    __shared__ float xs[64 * XPAD];  // 33 KB
    const int t = threadIdx.x;
    const int bbase = blockIdx.x * 64;
    const int wave = t >> 6;
    const int lane = t & 63;
    const int half = lane >> 5;
    const int sub = (lane >> 4) & 1;
    const int c8 = (lane & 15) * 8;

    GATHER_FP16_TILE(xh)
    __syncthreads();

    const int jg = __builtin_amdgcn_readfirstlane(wave) & 7;
    const int j0 = jg * 16;
    const float* Wj = W + j0;
    const float* xrow = xs + lane * XPAD;

    float acc[16];
#pragma unroll
    for (int q = 0; q < 16; ++q) acc[q] = 0.f;

#pragma unroll 2
    for (int k = 0; k < 128; k += 4) {
        float x0 = xrow[k + 0];
        float x1 = xrow[k + 1];
        float x2 = xrow[k + 2];
        float x3 = xrow[k + 3];
        const float* w0 = Wj + (size_t)k * 128;
#pragma unroll
        for (int q = 0; q < 16; ++q) {
            acc[q] += x0 * w0[q] + x1 * w0[128 + q] + x2 * w0[256 + q] + x3 * w0[384 + q];
        }
    }

    int node = bbase + lane;
    if (node < n) {
        float s = dout_is[node];
        float v[16];
#pragma unroll
        for (int q = 0; q < 16; ++q) {
            float u = acc[q] + b[j0 + q];
            u = fmaxf(u, LRELU_SLOPE * u);
            v[q] = u * s;
        }
        sth16(xh_out + (size_t)node * 128 + j0, v);
    }
}

// ------- layer 4+5 fused: fp16 gather -> GEMM(W4) -> @W5 -> h5 -------

__global__ __launch_bounds__(512) void k_gl128f(const __half* __restrict__ xh, const int* __restrict__ csr,
                                                const unsigned* __restrict__ row_ptr,
                                                const float* __restrict__ din_is, const float* __restrict__ dout_is,
                                                const float* __restrict__ W, const float* __restrict__ b,
                                                const float* __restrict__ W5,
                                                float* __restrict__ h5, int n) {
    __shared__ float xs[64 * XPAD];  // 33 KB (reused for the L5 reduction)
    const int t = threadIdx.x;
    const int bbase = blockIdx.x * 64;
    const int wave = t >> 6;
    const int lane = t & 63;
    const int half = lane >> 5;
    const int sub = (lane >> 4) & 1;
    const int c8 = (lane & 15) * 8;

    GATHER_FP16_TILE(xh)
    __syncthreads();

    const int jg = __builtin_amdgcn_readfirstlane(wave) & 7;
    const int j0 = jg * 16;
    const float* Wj = W + j0;
    const float* xrow = xs + lane * XPAD;

    float acc[16];
#pragma unroll
    for (int q = 0; q < 16; ++q) acc[q] = 0.f;

#pragma unroll 2
    for (int k = 0; k < 128; k += 4) {
        float x0 = xrow[k + 0];
        float x1 = xrow[k + 1];
        float x2 = xrow[k + 2];
        float x3 = xrow[k + 3];
        const float* w0 = Wj + (size_t)k * 128;
#pragma unroll
        for (int q = 0; q < 16; ++q) {
            acc[q] += x0 * w0[q] + x1 * w0[128 + q] + x2 * w0[256 + q] + x3 * w0[384 + q];
        }
    }

    // epilogue: xp4 cols -> partial (xp4 @ W5) 3-vector per (node, wave)
    float s = (bbase + lane < n) ? dout_is[bbase + lane] : 0.f;
    float p0 = 0.f, p1 = 0.f, p2 = 0.f;
#pragma unroll
    for (int q = 0; q < 16; ++q) {
        float u = acc[q] + b[j0 + q];
        u = fmaxf(u, LRELU_SLOPE * u);
        u *= s;
        const float* w5r = W5 + (size_t)(j0 + q) * 3;
        p0 = fmaf(u, w5r[0], p0);
        p1 = fmaf(u, w5r[1], p1);
        p2 = fmaf(u, w5r[2], p2);
    }
    __syncthreads();  // xs reads done; reuse as reduction scratch
    float* red = xs;  // layout: [node(64)][wave(8)][3]
    red[lane * 24 + wave * 3 + 0] = p0;
    red[lane * 24 + wave * 3 + 1] = p1;
    red[lane * 24 + wave * 3 + 2] = p2;
    __syncthreads();
    if (t < 64) {
        int node = bbase + t;
        if (node < n) {
            float a0 = 0.f, a1 = 0.f, a2 = 0.f;
#pragma unroll
            for (int w = 0; w < 8; ++w) {
                a0 += red[t * 24 + w * 3 + 0];
                a1 += red[t * 24 + w * 3 + 1];
                a2 += red[t * 24 + w * 3 + 2];
            }
            h5[(size_t)node * 3 + 0] = a0;
            h5[(size_t)node * 3 + 1] = a1;
            h5[(size_t)node * 3 + 2] = a2;
        }
    }
}

// ---------------- final 3-wide gather ----------------

__global__ void k_gather3(const float* __restrict__ h, const int* __restrict__ csr,
                          const unsigned* __restrict__ row_ptr, const float* __restrict__ din_is,
                          const float* __restrict__ b, float* __restrict__ out, int n) {
    int i = blockIdx.x * blockDim.x + threadIdx.x;
    if (i >= n) return;
    unsigned beg = row_ptr[i], end = row_ptr[i + 1];
    float a0 = 0.f, a1 = 0.f, a2 = 0.f;
    for (unsigned e = beg; e < end; ++e) {
        int s = csr[e];
        a0 += h[(size_t)s * 3 + 0];
        a1 += h[(size_t)s * 3 + 1];
        a2 += h[(size_t)s * 3 + 2];
    }
    float di = din_is[i];
    out[(size_t)i * 3 + 0] = a0 * di + b[0];
    out[(size_t)i * 3 + 1] = a1 * di + b[1];
    out[(size_t)i * 3 + 2] = a2 * di + b[2];
}

// ---------------- launch ----------------

extern "C" void kernel_launch(void* const* d_in, const int* in_sizes, int n_in,
                              void* d_out, int out_size, void* d_ws, size_t ws_size,
                              hipStream_t stream) {
    const float* features = (const float*)d_in[0];
    const int* esrc = (const int*)d_in[1];
    const int* edst = (const int*)d_in[2];
    const float* W1 = (const float*)d_in[3];  const float* b1 = (const float*)d_in[4];
    const float* W2 = (const float*)d_in[5];  const float* b2 = (const float*)d_in[6];
    const float* W3 = (const float*)d_in[7];  const float* b3 = (const float*)d_in[8];
    const float* W4 = (const float*)d_in[9];  const float* b4 = (const float*)d_in[10];
    const float* W5 = (const float*)d_in[11]; const float* b5 = (const float*)d_in[12];

    const int N = in_sizes[0] / 4;
    const int E = in_sizes[1];
    const int nbuck = (N + 255) / 256;
    const int NPB = 256;

    size_t off = 0;
    auto carve = [&](size_t bytes) -> void* {
        void* p = (char*)d_ws + off;
        off = (off + bytes + 255) & ~(size_t)255;
        return p;
    };
    char*     scratch   = (char*)carve((size_t)E * 12 + 256);   // pairs + srcbuf
    float*    Bp        = (float*)carve((size_t)N * 8 * 4);     // pf4 + a4
    __half*   xh2       = (__half*)carve((size_t)N * 128 * 2);
    __half*   xh3       = (__half*)carve((size_t)N * 128 * 2);
    float*    A         = (float*)carve((size_t)N * 3 * 4);     // h5
    int*      csr       = (int*)carve((size_t)E * 4);
    unsigned* row_ptr   = (unsigned*)carve((size_t)(N + 1) * 4);
    unsigned* dout_cnt  = (unsigned*)carve((size_t)N * 4);
    unsigned* din_cnt   = (unsigned*)carve((size_t)N * 4);
    float*    dout_is   = (float*)carve((size_t)N * 4);
    float*    din_is    = (float*)carve((size_t)N * 4);
    unsigned* gHistD    = (unsigned*)carve((size_t)MAXBUCK * 4);
    unsigned* gHistS    = (unsigned*)carve((size_t)MAXBUCK * 4);
    unsigned* bstartD   = (unsigned*)carve((size_t)(MAXBUCK + 1) * 4);
    unsigned* bstartS   = (unsigned*)carve((size_t)(MAXBUCK + 1) * 4);
    unsigned* blockBaseD = (unsigned*)carve((size_t)NPB * nbuck * 4);
    unsigned* blockBaseS = (unsigned*)carve((size_t)NPB * nbuck * 4);
    (void)ws_size;
    int2* pairs  = (int2*)scratch;
    int*  srcbuf = (int*)(scratch + (size_t)E * 8);
    float* pf4 = Bp;
    float* a4  = Bp + (size_t)N * 4;
    float* h5  = A;

    hipMemsetAsync(gHistD, 0, (size_t)MAXBUCK * 4, stream);
    hipMemsetAsync(gHistS, 0, (size_t)MAXBUCK * 4, stream);

    // ---- bucket-partition preprocessing ----
    k_part_hist2<<<NPB, 256, 0, stream>>>(esrc, edst, E, nbuck, gHistS, gHistD, blockBaseS, blockBaseD);
    k_part_scan2<<<1, 512, 0, stream>>>(gHistD, gHistS, nbuck, bstartD, bstartS, row_ptr + N, (unsigned)E);
    k_part_scatter_both<<<NPB, 256, 0, stream>>>(esrc, edst, E, nbuck, bstartS, bstartD,
                                                 blockBaseS, blockBaseD, pairs, srcbuf);
    k_bucket_csr<<<nbuck, 256, 0, stream>>>(pairs, bstartD, row_ptr, din_cnt, csr, N);
    k_bucket_cnt<<<nbuck, 256, 0, stream>>>(srcbuf, bstartS, dout_cnt, N);
    k_invsqrt2<<<(N + 255) / 256, 256, 0, stream>>>(dout_cnt, dout_is, din_cnt, din_is, N);

    // ---- layer 1 prep: 4-wide prescale + aggregate ----
    k_prescale4<<<(N + 255) / 256, 256, 0, stream>>>(features, dout_is, pf4, N);
    k_gather4<<<(N + 255) / 256, 256, 0, stream>>>(pf4, csr, row_ptr, din_is, dout_is, a4, N);

    // ---- layers 1+2 fused -> fp16; L3 fp16; L4+L5 fused -> h5 ----
    int glGrid = (N + 63) / 64;
    k_gl12<<<glGrid, 512, 0, stream>>>(a4, dout_is, csr, row_ptr, din_is, dout_is, W1, b1, W2, b2, xh2, N);
    k_gl128h<<<glGrid, 512, 0, stream>>>(xh2, csr, row_ptr, din_is, dout_is, W3, b3, xh3, N);
    k_gl128f<<<glGrid, 512, 0, stream>>>(xh3, csr, row_ptr, din_is, dout_is, W4, b4, W5, h5, N);

    // ---- final gather ----
    k_gather3<<<(N + 255) / 256, 256, 0, stream>>>(h5, csr, row_ptr, din_is, b5, (float*)d_out, N);
}